// Round 5
// baseline (385.667 us; speedup 1.0000x reference)
//
#include <hip/hip_runtime.h>
#include <math.h>

#define SEQ 4096
#define DIM 256
#define NH 8
#define DHD 32
#define FFD 1024
#define NLAYER 4

typedef unsigned short ushort_t;
typedef __attribute__((ext_vector_type(8))) short bf16x8;
typedef __attribute__((ext_vector_type(4))) float f32x4;

__device__ __forceinline__ float gelu_f(float x){
  const float c = 0.7978845608028654f; // sqrt(2/pi)
  float x3 = x*x*x;
  return 0.5f * x * (1.0f + tanhf(c*(x + 0.044715f*x3)));
}

__device__ __forceinline__ ushort_t f2b(float f){
  union { float f; unsigned u; } x; x.f = f;
  unsigned r = x.u + 0x7FFF + ((x.u >> 16) & 1);   // RNE
  return (ushort_t)(r >> 16);
}

// async 16B global->LDS (dest = wave-uniform base + lane*16, lane-contiguous)
__device__ __forceinline__ void gload16(void* lds, const void* g){
  __builtin_amdgcn_global_load_lds((const __attribute__((address_space(1))) void*)g,
                                   (__attribute__((address_space(3))) void*)lds, 16, 0, 0);
}

// ---------------- weight convert + transpose: W[K][N] fp32 -> Wt[N][K] bf16 --
__global__ __launch_bounds__(256) void wconv_kernel(
    const float* __restrict__ wq, const float* __restrict__ wk,
    const float* __restrict__ wv, const float* __restrict__ wo,
    const float* __restrict__ w1, const float* __restrict__ w2,
    ushort_t* __restrict__ wt){
  __shared__ ushort_t tile[64][65];
  int b = blockIdx.x, tid = threadIdx.x;
  const float* src; ushort_t* dst; int K, N, tk, tn;
  if (b < 256){
    int m = b>>6, rem = b&63, l = rem>>4, t = rem&15;
    K = 256; N = 256; tk = t>>2; tn = t&3;
    const float* s4 = (m==0)?wq:(m==1)?wk:(m==2)?wv:wo;
    src = s4 + (size_t)l*65536;
    dst = wt + (size_t)(m*NLAYER + l)*65536;
  } else if (b < 512){
    int rem = b-256, l = rem>>6, t = rem&63;
    K = 256; N = 1024; tk = t>>4; tn = t&15;
    src = w1 + (size_t)l*262144;
    dst = wt + 1048576 + (size_t)l*262144;
  } else {
    int rem = b-512, l = rem>>6, t = rem&63;
    K = 1024; N = 256; tk = t>>2; tn = t&3;
    src = w2 + (size_t)l*262144;
    dst = wt + 2097152 + (size_t)l*262144;
  }
  int k0 = tk*64, n0 = tn*64;
  #pragma unroll
  for (int i=0;i<16;i++){
    int idx = tid + 256*i, row = idx>>6, col = idx&63;
    tile[row][col] = f2b(src[(size_t)(k0+row)*N + n0+col]);
  }
  __syncthreads();
  #pragma unroll
  for (int i=0;i<16;i++){
    int idx = tid + 256*i, nrow = idx>>6, kcol = idx&63;
    dst[(size_t)(n0+nrow)*K + k0+kcol] = tile[kcol][nrow];
  }
}

// ---------------- LayerNorm: fp32 in, fp32 + bf16 out (LN2) -----------------
__global__ __launch_bounds__(256) void ln_kernel(const float* __restrict__ x,
    float* __restrict__ yf, ushort_t* __restrict__ yb){
  int row  = blockIdx.x*4 + (threadIdx.x>>6);
  int lane = threadIdx.x & 63;
  const float4* xr = (const float4*)(x + (size_t)row*DIM);
  float4 v = xr[lane];
  float s  = v.x+v.y+v.z+v.w;
  float sq = v.x*v.x+v.y*v.y+v.z*v.z+v.w*v.w;
  #pragma unroll
  for(int off=32; off>0; off>>=1){
    s  += __shfl_down(s, off);
    sq += __shfl_down(sq, off);
  }
  s = __shfl(s, 0); sq = __shfl(sq, 0);
  float mean = s * (1.0f/DIM);
  float var  = sq * (1.0f/DIM) - mean*mean;
  float rinv = rsqrtf(var + 1e-5f);
  float4 o;
  o.x=(v.x-mean)*rinv; o.y=(v.y-mean)*rinv; o.z=(v.z-mean)*rinv; o.w=(v.w-mean)*rinv;
  if (yf) ((float4*)(yf + (size_t)row*DIM))[lane] = o;
  if (yb){
    ushort_t* yp = yb + (size_t)row*DIM + lane*4;
    yp[0]=f2b(o.x); yp[1]=f2b(o.y); yp[2]=f2b(o.z); yp[3]=f2b(o.w);
  }
}

// ---------------- bf16 MFMA GEMM: C = act(A @ Wt^T + bias (+R)) --------------
// 64x64 block tile, 2x2 waves, wave-tile 32x32 (acc[2][2]): 4 ds_read_b128
// feed 4 MFMAs per K=32 step. K staged 256/step, XOR chunk-swizzle, gload_lds.
// LDS 64KB -> 2 blocks/CU.
__global__ __launch_bounds__(256) void gemm_kernel(
    const ushort_t* __restrict__ A, const ushort_t* __restrict__ Wt,
    const float* __restrict__ bias, const float* __restrict__ R,
    float* __restrict__ Cf, ushort_t* __restrict__ Cb,
    int M, int N, int K, int act){
  __shared__ ushort_t As[64*256];
  __shared__ ushort_t Bs[64*256];
  int tid = threadIdx.x;
  int w = tid>>6, lane = tid&63;
  int wr = w>>1, wc = w&1;
  int q4 = lane>>4, u = lane&15;
  int m0 = blockIdx.y*64, n0 = blockIdx.x*64;
  f32x4 acc[2][2];
  #pragma unroll
  for (int i=0;i<2;i++)
    #pragma unroll
    for (int j=0;j<2;j++)
      acc[i][j] = (f32x4){0.f,0.f,0.f,0.f};

  for (int k0 = 0; k0 < K; k0 += 256){
    if (k0) __syncthreads();
    #pragma unroll
    for (int i=0;i<8;i++){          // As: 64 rows x 32 chunks of 16B
      int idx = tid + 256*i;
      int row = idx>>5, ch = idx&31;
      gload16(&As[idx*8], &A[(size_t)(m0+row)*K + k0 + ((ch^(row&7))*8)]);
    }
    #pragma unroll
    for (int i=0;i<8;i++){          // Bs: 64 rows x 32 chunks
      int idx = tid + 256*i;
      int row = idx>>5, ch = idx&31;
      gload16(&Bs[idx*8], &Wt[(size_t)(n0+row)*K + k0 + ((ch^(row&7))*8)]);
    }
    __syncthreads();
    #pragma unroll
    for (int kk=0;kk<8;kk++){
      bf16x8 af[2], bf[2];
      #pragma unroll
      for (int i=0;i<2;i++){
        int ar = wr*32 + i*16 + u;
        af[i] = *(const bf16x8*)&As[ar*256 + (((kk*4+q4)^(ar&7))*8)];
      }
      #pragma unroll
      for (int j=0;j<2;j++){
        int br = wc*32 + j*16 + u;
        bf[j] = *(const bf16x8*)&Bs[br*256 + (((kk*4+q4)^(br&7))*8)];
      }
      #pragma unroll
      for (int i=0;i<2;i++)
        #pragma unroll
        for (int j=0;j<2;j++)
          acc[i][j] = __builtin_amdgcn_mfma_f32_16x16x32_bf16(af[i], bf[j], acc[i][j], 0, 0, 0);
    }
  }
  #pragma unroll
  for (int i=0;i<2;i++){
    #pragma unroll
    for (int j=0;j<2;j++){
      #pragma unroll
      for (int t=0;t<4;t++){
        int m = m0 + wr*32 + i*16 + q4*4 + t;
        int n = n0 + wc*32 + j*16 + u;
        float val = acc[i][j][t] + bias[n];
        if (R)   val += R[(size_t)m*N + n];
        if (act) val = gelu_f(val);
        if (Cf)  Cf[(size_t)m*N + n] = val;
        if (Cb)  Cb[(size_t)m*N + n] = f2b(val);
      }
    }
  }
}

// ---------------- fused LN + QKV: q/k/v = LN(h) @ W + b, bf16 out -----------
// 64x64 block tile; LN once into As, then 3 weight stagings (z-loop internal).
// Next-z B-stage issued before the current epilogue so gload latency hides
// under the global stores.
__global__ __launch_bounds__(256) void qkv_kernel(
    const float* __restrict__ hin,
    const ushort_t* __restrict__ wtq, const ushort_t* __restrict__ wtk, const ushort_t* __restrict__ wtv,
    const float* __restrict__ bqp, const float* __restrict__ bkp, const float* __restrict__ bvp,
    ushort_t* __restrict__ qo, ushort_t* __restrict__ ko, ushort_t* __restrict__ vo){
  __shared__ ushort_t As[64*256];
  __shared__ ushort_t Bs[64*256];
  int tid = threadIdx.x;
  int w = tid>>6, lane = tid&63;
  int wr = w>>1, wc = w&1;
  int q4 = lane>>4, u = lane&15;
  int m0 = blockIdx.y*64, n0 = blockIdx.x*64;

  // stage B for z=0 immediately; lands by the post-LN barrier
  #pragma unroll
  for (int i=0;i<8;i++){
    int idx = tid + 256*i;
    int row = idx>>5, ch = idx&31;
    gload16(&Bs[idx*8], &wtq[(size_t)(n0+row)*DIM + ((ch^(row&7))*8)]);
  }
  // LN rows m0..m0+63: wave w handles rows w*16..w*16+15 (full-wave reduce)
  #pragma unroll
  for (int r=0;r<16;r++){
    int row = w*16 + r;
    float4 v = *(const float4*)&hin[(size_t)(m0+row)*DIM + lane*4];
    float s  = v.x+v.y+v.z+v.w;
    float sq = v.x*v.x+v.y*v.y+v.z*v.z+v.w*v.w;
    #pragma unroll
    for (int off=32; off>0; off>>=1){ s += __shfl_down(s,off); sq += __shfl_down(sq,off); }
    s = __shfl(s,0); sq = __shfl(sq,0);
    float mean = s*(1.0f/DIM), var = sq*(1.0f/DIM) - mean*mean;
    float rinv = rsqrtf(var + 1e-5f);
    int ch = lane>>1, half = lane&1;
    ushort4 o4;
    o4.x = f2b((v.x-mean)*rinv); o4.y = f2b((v.y-mean)*rinv);
    o4.z = f2b((v.z-mean)*rinv); o4.w = f2b((v.w-mean)*rinv);
    *(ushort4*)&As[row*256 + ((ch^(row&7))*8 + half*4)] = o4;
  }
  __syncthreads();

  #pragma unroll
  for (int z=0; z<3; z++){
    const float* bias = (z==0)?bqp:(z==1)?bkp:bvp;
    ushort_t* Cb      = (z==0)?qo :(z==1)?ko :vo;
    f32x4 acc[2][2];
    #pragma unroll
    for (int i=0;i<2;i++)
      #pragma unroll
      for (int j=0;j<2;j++)
        acc[i][j] = (f32x4){0.f,0.f,0.f,0.f};
    #pragma unroll
    for (int kk=0;kk<8;kk++){
      bf16x8 af[2], bf[2];
      #pragma unroll
      for (int i=0;i<2;i++){
        int ar = wr*32 + i*16 + u;
        af[i] = *(const bf16x8*)&As[ar*256 + (((kk*4+q4)^(ar&7))*8)];
      }
      #pragma unroll
      for (int j=0;j<2;j++){
        int br = wc*32 + j*16 + u;
        bf[j] = *(const bf16x8*)&Bs[br*256 + (((kk*4+q4)^(br&7))*8)];
      }
      #pragma unroll
      for (int i=0;i<2;i++)
        #pragma unroll
        for (int j=0;j<2;j++)
          acc[i][j] = __builtin_amdgcn_mfma_f32_16x16x32_bf16(af[i], bf[j], acc[i][j], 0, 0, 0);
    }
    if (z < 2){
      __syncthreads();   // all waves' Bs reads complete
      const ushort_t* Wn = (z==0)?wtk:wtv;
      #pragma unroll
      for (int i=0;i<8;i++){
        int idx = tid + 256*i;
        int row = idx>>5, ch = idx&31;
        gload16(&Bs[idx*8], &Wn[(size_t)(n0+row)*DIM + ((ch^(row&7))*8)]);
      }
    }
    #pragma unroll
    for (int i=0;i<2;i++)
      #pragma unroll
      for (int j=0;j<2;j++)
        #pragma unroll
        for (int t=0;t<4;t++){
          int m = m0 + wr*32 + i*16 + q4*4 + t;
          int n = n0 + wc*32 + j*16 + u;
          Cb[(size_t)m*DIM + n] = f2b(acc[i][j][t] + bias[n]);
        }
    if (z < 2) __syncthreads();   // next B landed (vmcnt drained)
  }
}

// ---------------- sliding-window attention, bf16 MFMA flash-style ----------
// grid (SEQ/64, NH), block 256 = 4 waves. Double-buffered K/V with async
// reg-staging (loads issued before QK^T, ds_write after PV): 1 barrier/tile.
__global__ __launch_bounds__(256) void attn_kernel(
    const ushort_t* __restrict__ q, const ushort_t* __restrict__ k,
    const ushort_t* __restrict__ v, ushort_t* __restrict__ out){
  int q0 = blockIdx.x * 64;
  int h  = blockIdx.y;
  int tid = threadIdx.x;
  int w = tid >> 6;
  int lane = tid & 63;
  int u = lane & 15, q4 = lane >> 4;

  __shared__ ushort_t Ks[2][64][40];    // [key][dh], 80B rows
  __shared__ ushort_t Vt[2][32][72];    // [dh][key], 144B rows
  __shared__ ushort_t Pw[4][16][72];    // per-wave P (wave-private)

  bf16x8 aq = *(const bf16x8*)(q + (size_t)(q0 + w*16 + u)*DIM + h*DHD + q4*8);

  float m[4], l[4];
  f32x4 acc[2];
  #pragma unroll
  for (int t=0;t<4;t++){ m[t] = -INFINITY; l[t] = 0.f; }
  acc[0] = (f32x4){0.f,0.f,0.f,0.f};
  acc[1] = (f32x4){0.f,0.f,0.f,0.f};

  const float sl2 = 0.25510703448358519f; // (1/sqrt(32)) * log2(e)

  int lo = q0 - 256; if (lo < 0) lo = 0;
  int hi = q0 + 63 + 256; if (hi > SEQ-1) hi = SEQ-1;
  int kt0 = (lo >> 6) << 6;
  int kt1 = (hi >> 6) << 6;

  int key = tid >> 2, d0 = (tid & 3) * 8;  // K-staging map
  int vd0 = w * 8;                          // V-staging: wave w -> dh slice

  // prologue: stage tile 0 into buf 0
  bf16x8 kr = *(const bf16x8*)(k + (size_t)(kt0+key)*DIM + h*DHD + d0);
  bf16x8 vr = *(const bf16x8*)(v + (size_t)(kt0+lane)*DIM + h*DHD + vd0);
  *(bf16x8*)&Ks[0][key][d0] = kr;
  #pragma unroll
  for (int j=0;j<8;j++) Vt[0][vd0+j][lane] = (ushort_t)vr[j];

  int p = 0;
  for (int kt = kt0; kt <= kt1; kt += 64, p ^= 1){
    __syncthreads();   // tile kt visible in buf p; all prior buf p^1 reads done
    bool have_next = (kt + 64 <= kt1);
    if (have_next){    // issue next tile's loads early; land under softmax+PV
      kr = *(const bf16x8*)(k + (size_t)(kt+64+key)*DIM + h*DHD + d0);
      vr = *(const bf16x8*)(v + (size_t)(kt+64+lane)*DIM + h*DHD + vd0);
    }

    f32x4 sc[4];
    #pragma unroll
    for (int t4=0;t4<4;t4++){
      bf16x8 bk = *(const bf16x8*)&Ks[p][t4*16 + u][q4*8];
      sc[t4] = __builtin_amdgcn_mfma_f32_16x16x32_bf16(aq, bk, (f32x4){0.f,0.f,0.f,0.f}, 0, 0, 0);
    }

    bool needs_mask = (kt < q0-192) || (kt > q0+192);
    #pragma unroll
    for (int t=0;t<4;t++){
      float mx = -INFINITY;
      if (needs_mask){
        int q_idx = q0 + w*16 + q4*4 + t;
        #pragma unroll
        for (int t4=0;t4<4;t4++){
          float s = sc[t4][t] * sl2;
          int k_idx = kt + t4*16 + u;
          int diff = q_idx - k_idx; if (diff < 0) diff = -diff;
          if (diff > 256) s = -INFINITY;
          sc[t4][t] = s;
          mx = fmaxf(mx, s);
        }
      } else {
        #pragma unroll
        for (int t4=0;t4<4;t4++){
          float s = sc[t4][t] * sl2;
          sc[t4][t] = s;
          mx = fmaxf(mx, s);
        }
      }
      mx = fmaxf(mx, __shfl_xor(mx, 1));
      mx = fmaxf(mx, __shfl_xor(mx, 2));
      mx = fmaxf(mx, __shfl_xor(mx, 4));
      mx = fmaxf(mx, __shfl_xor(mx, 8));
      float nm = fmaxf(m[t], mx);
      float al = exp2f(m[t] - nm);
      float rs = 0.f;
      #pragma unroll
      for (int t4=0;t4<4;t4++){
        float pv = exp2f(sc[t4][t] - nm);
        rs += pv;
        Pw[w][q4*4+t][t4*16+u] = f2b(pv);
      }
      rs += __shfl_xor(rs, 1);
      rs += __shfl_xor(rs, 2);
      rs += __shfl_xor(rs, 4);
      rs += __shfl_xor(rs, 8);
      l[t] = l[t]*al + rs;
      m[t] = nm;
      acc[0][t] *= al;
      acc[1][t] *= al;
    }
    // PV (Pw wave-private -> no barrier; Vt fenced by loop-top barrier)
    #pragma unroll
    for (int kk=0;kk<2;kk++){
      bf16x8 ap = *(const bf16x8*)&Pw[w][u][kk*32 + q4*8];
      #pragma unroll
      for (int d=0; d<2; d++){
        bf16x8 bvf = *(const bf16x8*)&Vt[p][d*16 + u][kk*32 + q4*8];
        acc[d] = __builtin_amdgcn_mfma_f32_16x16x32_bf16(ap, bvf, acc[d], 0, 0, 0);
      }
    }
    if (have_next){    // write next tile into the other buffer
      *(bf16x8*)&Ks[p^1][key][d0] = kr;
      #pragma unroll
      for (int j=0;j<8;j++) Vt[p^1][vd0+j][lane] = (ushort_t)vr[j];
    }
  }

  float rl[4];
  #pragma unroll
  for (int t=0;t<4;t++) rl[t] = 1.0f / l[t];
  #pragma unroll
  for (int d=0; d<2; d++)
    #pragma unroll
    for (int t=0;t<4;t++)
      out[(size_t)(q0 + w*16 + q4*4 + t)*DIM + h*DHD + d*16 + u] = f2b(acc[d][t]*rl[t]);
}

extern "C" void kernel_launch(void* const* d_in, const int* in_sizes, int n_in,
                              void* d_out, int out_size, void* d_ws, size_t ws_size,
                              hipStream_t stream) {
  const float* x  = (const float*)d_in[0];
  const float* wq = (const float*)d_in[1];
  const float* bq = (const float*)d_in[2];
  const float* wk = (const float*)d_in[3];
  const float* bk = (const float*)d_in[4];
  const float* wv = (const float*)d_in[5];
  const float* bv = (const float*)d_in[6];
  const float* wo = (const float*)d_in[7];
  const float* bo = (const float*)d_in[8];
  const float* w1 = (const float*)d_in[9];
  const float* b1 = (const float*)d_in[10];
  const float* w2 = (const float*)d_in[11];
  const float* b2 = (const float*)d_in[12];
  float* out = (float*)d_out;
  float* ws  = (float*)d_ws;

  // workspace layout (float offsets)
  ushort_t* wt    = (ushort_t*)ws;                    // converted weights (bf16)
  ushort_t* abuf  = (ushort_t*)(ws + 1572864);        // attn-out / LN2-out bf16
  ushort_t* ffbf  = (ushort_t*)(ws + 2097152);        // FFN1 out bf16
  float* qb = ws + 4194304;                           // q (bf16) -> later h1 (fp32)
  float* kb = ws + 5242880;                           // k (bf16) -> later h2 (fp32)
  float* vb = ws + 6291456;                           // v (bf16)
  float* hb = ws + 7340032;                           // layer carry
  ushort_t* qbh = (ushort_t*)qb;
  ushort_t* kbh = (ushort_t*)kb;
  ushort_t* vbh = (ushort_t*)vb;

  const ushort_t* w1t_base = wt + 1048576;
  const ushort_t* w2t_base = wt + 2097152;

  const dim3 blk(256);
  wconv_kernel<<<768, blk, 0, stream>>>(wq, wk, wv, wo, w1, w2, wt);

  for (int l = 0; l < NLAYER; l++){
    const float* hin = (l == 0) ? x : hb;
    const ushort_t* lwq = wt + (size_t)(0*NLAYER + l)*65536;
    const ushort_t* lwk = wt + (size_t)(1*NLAYER + l)*65536;
    const ushort_t* lwv = wt + (size_t)(2*NLAYER + l)*65536;
    const ushort_t* lwo = wt + (size_t)(3*NLAYER + l)*65536;
    const ushort_t* lw1 = w1t_base + (size_t)l*262144;
    const ushort_t* lw2 = w2t_base + (size_t)l*262144;

    // q,k,v = LN(h)@W + b (fused LN1 + internal z-loop, bf16 out)
    qkv_kernel<<<dim3(4,64), blk, 0, stream>>>(hin, lwq, lwk, lwv,
        bq + (size_t)l*DIM, bk + (size_t)l*DIM, bv + (size_t)l*DIM, qbh, kbh, vbh);
    // attention (MFMA flash) -> bf16 abuf
    attn_kernel<<<dim3(SEQ/64, NH), blk, 0, stream>>>(qbh, kbh, vbh, abuf);
    // h1 = h + attn@wo + bo -> qb (fp32)
    gemm_kernel<<<dim3(4,64), blk, 0, stream>>>(abuf, lwo, bo + (size_t)l*DIM,
        hin, qb, nullptr, SEQ, DIM, DIM, 0);
    // h2 = LN(h1) -> kb (fp32) + abuf (bf16)
    ln_kernel<<<SEQ/4, blk, 0, stream>>>(qb, kb, abuf);
    // ff = gelu(h2@w1 + b1) -> bf16
    gemm_kernel<<<dim3(16,64), blk, 0, stream>>>(abuf, lw1, b1 + (size_t)l*FFD,
        nullptr, nullptr, ffbf, SEQ, FFD, DIM, 1);
    // h_out = h2 + ff@w2 + b2
    float* hout = (l == NLAYER-1) ? out : hb;
    gemm_kernel<<<dim3(4,64), blk, 0, stream>>>(ffbf, lw2, b2 + (size_t)l*DIM,
        kb, hout, nullptr, SEQ, DIM, FFD, 0);
  }
}

// Round 8
// 360.534 us; speedup vs baseline: 1.0697x; 1.0697x over previous
//
#include <hip/hip_runtime.h>
#include <math.h>

#define SEQ 4096
#define DIM 256
#define NH 8
#define DHD 32
#define FFD 1024
#define NLAYER 4

typedef unsigned short ushort_t;
typedef __attribute__((ext_vector_type(8))) short bf16x8;
typedef __attribute__((ext_vector_type(4))) float f32x4;

__device__ __forceinline__ float gelu_f(float x){
  const float c = 0.7978845608028654f; // sqrt(2/pi)
  float x3 = x*x*x;
  return 0.5f * x * (1.0f + tanhf(c*(x + 0.044715f*x3)));
}

__device__ __forceinline__ ushort_t f2b(float f){
  union { float f; unsigned u; } x; x.f = f;
  unsigned r = x.u + 0x7FFF + ((x.u >> 16) & 1);   // RNE
  return (ushort_t)(r >> 16);
}

// async 16B global->LDS (dest = wave-uniform base + lane*16, lane-contiguous)
__device__ __forceinline__ void gload16(void* lds, const void* g){
  __builtin_amdgcn_global_load_lds((const __attribute__((address_space(1))) void*)g,
                                   (__attribute__((address_space(3))) void*)lds, 16, 0, 0);
}

// ---------------- weight convert + transpose: W[K][N] fp32 -> Wt[N][K] bf16 --
__global__ __launch_bounds__(256) void wconv_kernel(
    const float* __restrict__ wq, const float* __restrict__ wk,
    const float* __restrict__ wv, const float* __restrict__ wo,
    const float* __restrict__ w1, const float* __restrict__ w2,
    ushort_t* __restrict__ wt){
  __shared__ ushort_t tile[64][65];
  int b = blockIdx.x, tid = threadIdx.x;
  const float* src; ushort_t* dst; int K, N, tk, tn;
  if (b < 256){
    int m = b>>6, rem = b&63, l = rem>>4, t = rem&15;
    K = 256; N = 256; tk = t>>2; tn = t&3;
    const float* s4 = (m==0)?wq:(m==1)?wk:(m==2)?wv:wo;
    src = s4 + (size_t)l*65536;
    dst = wt + (size_t)(m*NLAYER + l)*65536;
  } else if (b < 512){
    int rem = b-256, l = rem>>6, t = rem&63;
    K = 256; N = 1024; tk = t>>4; tn = t&15;
    src = w1 + (size_t)l*262144;
    dst = wt + 1048576 + (size_t)l*262144;
  } else {
    int rem = b-512, l = rem>>6, t = rem&63;
    K = 1024; N = 256; tk = t>>2; tn = t&3;
    src = w2 + (size_t)l*262144;
    dst = wt + 2097152 + (size_t)l*262144;
  }
  int k0 = tk*64, n0 = tn*64;
  #pragma unroll
  for (int i=0;i<16;i++){
    int idx = tid + 256*i, row = idx>>6, col = idx&63;
    tile[row][col] = f2b(src[(size_t)(k0+row)*N + n0+col]);
  }
  __syncthreads();
  #pragma unroll
  for (int i=0;i<16;i++){
    int idx = tid + 256*i, nrow = idx>>6, kcol = idx&63;
    dst[(size_t)(n0+nrow)*K + k0+kcol] = tile[kcol][nrow];
  }
}

// ---------------- LayerNorm: fp32 in, fp32 + bf16 out (LN2) -----------------
__global__ __launch_bounds__(256) void ln_kernel(const float* __restrict__ x,
    float* __restrict__ yf, ushort_t* __restrict__ yb){
  int row  = blockIdx.x*4 + (threadIdx.x>>6);
  int lane = threadIdx.x & 63;
  const float4* xr = (const float4*)(x + (size_t)row*DIM);
  float4 v = xr[lane];
  float s  = v.x+v.y+v.z+v.w;
  float sq = v.x*v.x+v.y*v.y+v.z*v.z+v.w*v.w;
  #pragma unroll
  for(int off=32; off>0; off>>=1){
    s  += __shfl_down(s, off);
    sq += __shfl_down(sq, off);
  }
  s = __shfl(s, 0); sq = __shfl(sq, 0);
  float mean = s * (1.0f/DIM);
  float var  = sq * (1.0f/DIM) - mean*mean;
  float rinv = rsqrtf(var + 1e-5f);
  float4 o;
  o.x=(v.x-mean)*rinv; o.y=(v.y-mean)*rinv; o.z=(v.z-mean)*rinv; o.w=(v.w-mean)*rinv;
  if (yf) ((float4*)(yf + (size_t)row*DIM))[lane] = o;
  if (yb){
    ushort_t* yp = yb + (size_t)row*DIM + lane*4;
    yp[0]=f2b(o.x); yp[1]=f2b(o.y); yp[2]=f2b(o.z); yp[3]=f2b(o.w);
  }
}

// ---------------- bf16 MFMA GEMM: C = act(A @ Wt^T + bias (+R)) --------------
// M-tile 32, N-tile 64, K staged 256 at a time (full-K for K=256 GEMMs).
// As[32][256] + Bs[64][256] = 48KB LDS -> 3 blocks/CU; grids >= 512 blocks.
// Staging: global_load_lds 16B with XOR chunk-swizzle (chunk ^= row&7) so the
// MFMA b128 reads (16 lanes, row-varying, 512B row stride) are conflict-free.
// 4 waves in 2x2: wave tile 16x32, 16 MFMAs per 256-K step.
__global__ __launch_bounds__(256) void gemm_kernel(
    const ushort_t* __restrict__ A, const ushort_t* __restrict__ Wt,
    const float* __restrict__ bias, const float* __restrict__ R,
    float* __restrict__ Cf, ushort_t* __restrict__ Cb,
    int M, int N, int K, int act){
  __shared__ ushort_t As[32*256];
  __shared__ ushort_t Bs[64*256];
  int tid = threadIdx.x;
  int w = tid>>6, lane = tid&63;
  int wr = w>>1, wc = w&1;
  int q4 = lane>>4, u = lane&15;
  int m0 = blockIdx.y*32, n0 = blockIdx.x*64;
  f32x4 acc[2];
  acc[0] = (f32x4){0.f,0.f,0.f,0.f};
  acc[1] = (f32x4){0.f,0.f,0.f,0.f};

  for (int k0 = 0; k0 < K; k0 += 256){
    if (k0) __syncthreads();
    #pragma unroll
    for (int i=0;i<4;i++){          // As: 32 rows x 32 chunks of 16B
      int idx = tid + 256*i;
      int row = idx>>5, ch = idx&31;
      gload16(&As[idx*8], &A[(size_t)(m0+row)*K + k0 + ((ch^(row&7))*8)]);
    }
    #pragma unroll
    for (int i=0;i<8;i++){          // Bs: 64 rows x 32 chunks
      int idx = tid + 256*i;
      int row = idx>>5, ch = idx&31;
      gload16(&Bs[idx*8], &Wt[(size_t)(n0+row)*K + k0 + ((ch^(row&7))*8)]);
    }
    __syncthreads();
    #pragma unroll
    for (int kk=0;kk<8;kk++){
      int ar = wr*16 + u;
      bf16x8 af = *(const bf16x8*)&As[ar*256 + (((kk*4+q4)^(ar&7))*8)];
      #pragma unroll
      for (int j=0;j<2;j++){
        int br = wc*32 + j*16 + u;
        bf16x8 bf = *(const bf16x8*)&Bs[br*256 + (((kk*4+q4)^(br&7))*8)];
        acc[j] = __builtin_amdgcn_mfma_f32_16x16x32_bf16(af, bf, acc[j], 0, 0, 0);
      }
    }
  }
  #pragma unroll
  for (int j=0;j<2;j++){
    #pragma unroll
    for (int t=0;t<4;t++){
      int m = m0 + wr*16 + q4*4 + t;
      int n = n0 + wc*32 + j*16 + u;
      float val = acc[j][t] + bias[n];
      if (R)   val += R[(size_t)m*N + n];
      if (act) val = gelu_f(val);
      if (Cf)  Cf[(size_t)m*N + n] = val;
      if (Cb)  Cb[(size_t)m*N + n] = f2b(val);
    }
  }
}

// ---------------- fused LN + QKV: q/k/v = LN(h) @ W + b, bf16 out -----------
// Same core as gemm_kernel but A is computed in-kernel: per-row LayerNorm of
// the fp32 carry, written bf16 into swizzled As via ds_write (K=DIM=256).
__global__ __launch_bounds__(256) void qkv_kernel(
    const float* __restrict__ hin,
    const ushort_t* __restrict__ wtq, const ushort_t* __restrict__ wtk, const ushort_t* __restrict__ wtv,
    const float* __restrict__ bqp, const float* __restrict__ bkp, const float* __restrict__ bvp,
    ushort_t* __restrict__ qo, ushort_t* __restrict__ ko, ushort_t* __restrict__ vo){
  __shared__ ushort_t As[32*256];
  __shared__ ushort_t Bs[64*256];
  int tid = threadIdx.x;
  int w = tid>>6, lane = tid&63;
  int wr = w>>1, wc = w&1;
  int q4 = lane>>4, u = lane&15;
  int m0 = blockIdx.y*32, n0 = blockIdx.x*64;

  // async-stage Bs first so HBM latency hides under the LN compute
  #pragma unroll
  for (int i=0;i<8;i++){
    int idx = tid + 256*i;
    int row = idx>>5, ch = idx&31;
    gload16(&Bs[idx*8], &wtq[(size_t)(n0+row)*DIM + ((ch^(row&7))*8)]);
  }
  // LN rows m0..m0+31: wave w handles rows w*8..w*8+7, full-wave reduce
  #pragma unroll
  for (int r=0;r<8;r++){
    int row = w*8 + r;
    float4 v = *(const float4*)&hin[(size_t)(m0+row)*DIM + lane*4];
    float s  = v.x+v.y+v.z+v.w;
    float sq = v.x*v.x+v.y*v.y+v.z*v.z+v.w*v.w;
    #pragma unroll
    for (int off=32; off>0; off>>=1){ s += __shfl_down(s,off); sq += __shfl_down(sq,off); }
    s = __shfl(s,0); sq = __shfl(sq,0);
    float mean = s*(1.0f/DIM), var = sq*(1.0f/DIM) - mean*mean;
    float rinv = rsqrtf(var + 1e-5f);
    int ch = lane>>1, half = lane&1;
    ushort4 o4;
    o4.x = f2b((v.x-mean)*rinv); o4.y = f2b((v.y-mean)*rinv);
    o4.z = f2b((v.z-mean)*rinv); o4.w = f2b((v.w-mean)*rinv);
    *(ushort4*)&As[row*256 + ((ch^(row&7))*8 + half*4)] = o4;
  }
  __syncthreads();

  #pragma unroll
  for (int z=0; z<3; z++){
    const float* bias = (z==0)?bqp:(z==1)?bkp:bvp;
    ushort_t* Cb      = (z==0)?qo :(z==1)?ko :vo;
    f32x4 acc[2];
    acc[0]=(f32x4){0.f,0.f,0.f,0.f}; acc[1]=(f32x4){0.f,0.f,0.f,0.f};
    #pragma unroll
    for (int kk=0;kk<8;kk++){
      int ar = wr*16 + u;
      bf16x8 af = *(const bf16x8*)&As[ar*256 + (((kk*4+q4)^(ar&7))*8)];
      #pragma unroll
      for (int j=0;j<2;j++){
        int br = wc*32 + j*16 + u;
        bf16x8 bf = *(const bf16x8*)&Bs[br*256 + (((kk*4+q4)^(br&7))*8)];
        acc[j] = __builtin_amdgcn_mfma_f32_16x16x32_bf16(af, bf, acc[j], 0, 0, 0);
      }
    }
    if (z < 2){
      __syncthreads();   // all waves' Bs reads complete
      const ushort_t* Wn = (z==0)?wtk:wtv;
      #pragma unroll
      for (int i=0;i<8;i++){
        int idx = tid + 256*i;
        int row = idx>>5, ch = idx&31;
        gload16(&Bs[idx*8], &Wn[(size_t)(n0+row)*DIM + ((ch^(row&7))*8)]);
      }
    }
    #pragma unroll
    for (int j=0;j<2;j++)
      #pragma unroll
      for (int t=0;t<4;t++){
        int m = m0 + wr*16 + q4*4 + t;
        int n = n0 + wc*32 + j*16 + u;
        Cb[(size_t)m*DIM + n] = f2b(acc[j][t] + bias[n]);
      }
    if (z < 2) __syncthreads();   // next B landed (vmcnt drained)
  }
}

// ---------------- sliding-window attention, bf16 MFMA flash-style ----------
// grid (SEQ/64, NH), block 256 = 4 waves. Double-buffered K/V with async
// reg-staging (loads issued before QK^T, ds_write after PV): 1 barrier/tile.
__global__ __launch_bounds__(256) void attn_kernel(
    const ushort_t* __restrict__ q, const ushort_t* __restrict__ k,
    const ushort_t* __restrict__ v, ushort_t* __restrict__ out){
  int q0 = blockIdx.x * 64;
  int h  = blockIdx.y;
  int tid = threadIdx.x;
  int w = tid >> 6;
  int lane = tid & 63;
  int u = lane & 15, q4 = lane >> 4;

  __shared__ ushort_t Ks[2][64][40];    // [key][dh], 80B rows
  __shared__ ushort_t Vt[2][32][72];    // [dh][key], 144B rows
  __shared__ ushort_t Pw[4][16][72];    // per-wave P (wave-private)

  bf16x8 aq = *(const bf16x8*)(q + (size_t)(q0 + w*16 + u)*DIM + h*DHD + q4*8);

  float m[4], l[4];
  f32x4 acc[2];
  #pragma unroll
  for (int t=0;t<4;t++){ m[t] = -INFINITY; l[t] = 0.f; }
  acc[0] = (f32x4){0.f,0.f,0.f,0.f};
  acc[1] = (f32x4){0.f,0.f,0.f,0.f};

  const float sl2 = 0.25510703448358519f; // (1/sqrt(32)) * log2(e)

  int lo = q0 - 256; if (lo < 0) lo = 0;
  int hi = q0 + 63 + 256; if (hi > SEQ-1) hi = SEQ-1;
  int kt0 = (lo >> 6) << 6;
  int kt1 = (hi >> 6) << 6;

  int key = tid >> 2, d0 = (tid & 3) * 8;  // K-staging map
  int vd0 = w * 8;                          // V-staging: wave w -> dh slice

  // prologue: stage tile 0 into buf 0
  bf16x8 kr = *(const bf16x8*)(k + (size_t)(kt0+key)*DIM + h*DHD + d0);
  bf16x8 vr = *(const bf16x8*)(v + (size_t)(kt0+lane)*DIM + h*DHD + vd0);
  *(bf16x8*)&Ks[0][key][d0] = kr;
  #pragma unroll
  for (int j=0;j<8;j++) Vt[0][vd0+j][lane] = (ushort_t)vr[j];

  int p = 0;
  for (int kt = kt0; kt <= kt1; kt += 64, p ^= 1){
    __syncthreads();   // tile kt visible in buf p; all prior buf p^1 reads done
    bool have_next = (kt + 64 <= kt1);
    if (have_next){    // issue next tile's loads early; land under softmax+PV
      kr = *(const bf16x8*)(k + (size_t)(kt+64+key)*DIM + h*DHD + d0);
      vr = *(const bf16x8*)(v + (size_t)(kt+64+lane)*DIM + h*DHD + vd0);
    }

    f32x4 sc[4];
    #pragma unroll
    for (int t4=0;t4<4;t4++){
      bf16x8 bk = *(const bf16x8*)&Ks[p][t4*16 + u][q4*8];
      sc[t4] = __builtin_amdgcn_mfma_f32_16x16x32_bf16(aq, bk, (f32x4){0.f,0.f,0.f,0.f}, 0, 0, 0);
    }

    bool needs_mask = (kt < q0-192) || (kt > q0+192);
    #pragma unroll
    for (int t=0;t<4;t++){
      float mx = -INFINITY;
      if (needs_mask){
        int q_idx = q0 + w*16 + q4*4 + t;
        #pragma unroll
        for (int t4=0;t4<4;t4++){
          float s = sc[t4][t] * sl2;
          int k_idx = kt + t4*16 + u;
          int diff = q_idx - k_idx; if (diff < 0) diff = -diff;
          if (diff > 256) s = -INFINITY;
          sc[t4][t] = s;
          mx = fmaxf(mx, s);
        }
      } else {
        #pragma unroll
        for (int t4=0;t4<4;t4++){
          float s = sc[t4][t] * sl2;
          sc[t4][t] = s;
          mx = fmaxf(mx, s);
        }
      }
      mx = fmaxf(mx, __shfl_xor(mx, 1));
      mx = fmaxf(mx, __shfl_xor(mx, 2));
      mx = fmaxf(mx, __shfl_xor(mx, 4));
      mx = fmaxf(mx, __shfl_xor(mx, 8));
      float nm = fmaxf(m[t], mx);
      float al = exp2f(m[t] - nm);
      float rs = 0.f;
      #pragma unroll
      for (int t4=0;t4<4;t4++){
        float pv = exp2f(sc[t4][t] - nm);
        rs += pv;
        Pw[w][q4*4+t][t4*16+u] = f2b(pv);
      }
      rs += __shfl_xor(rs, 1);
      rs += __shfl_xor(rs, 2);
      rs += __shfl_xor(rs, 4);
      rs += __shfl_xor(rs, 8);
      l[t] = l[t]*al + rs;
      m[t] = nm;
      acc[0][t] *= al;
      acc[1][t] *= al;
    }
    // PV (Pw wave-private -> no barrier; Vt fenced by loop-top barrier)
    #pragma unroll
    for (int kk=0;kk<2;kk++){
      bf16x8 ap = *(const bf16x8*)&Pw[w][u][kk*32 + q4*8];
      #pragma unroll
      for (int d=0; d<2; d++){
        bf16x8 bvf = *(const bf16x8*)&Vt[p][d*16 + u][kk*32 + q4*8];
        acc[d] = __builtin_amdgcn_mfma_f32_16x16x32_bf16(ap, bvf, acc[d], 0, 0, 0);
      }
    }
    if (have_next){    // write next tile into the other buffer
      *(bf16x8*)&Ks[p^1][key][d0] = kr;
      #pragma unroll
      for (int j=0;j<8;j++) Vt[p^1][vd0+j][lane] = (ushort_t)vr[j];
    }
  }

  float rl[4];
  #pragma unroll
  for (int t=0;t<4;t++) rl[t] = 1.0f / l[t];
  #pragma unroll
  for (int d=0; d<2; d++)
    #pragma unroll
    for (int t=0;t<4;t++)
      out[(size_t)(q0 + w*16 + q4*4 + t)*DIM + h*DHD + d*16 + u] = f2b(acc[d][t]*rl[t]);
}

extern "C" void kernel_launch(void* const* d_in, const int* in_sizes, int n_in,
                              void* d_out, int out_size, void* d_ws, size_t ws_size,
                              hipStream_t stream) {
  const float* x  = (const float*)d_in[0];
  const float* wq = (const float*)d_in[1];
  const float* bq = (const float*)d_in[2];
  const float* wk = (const float*)d_in[3];
  const float* bk = (const float*)d_in[4];
  const float* wv = (const float*)d_in[5];
  const float* bv = (const float*)d_in[6];
  const float* wo = (const float*)d_in[7];
  const float* bo = (const float*)d_in[8];
  const float* w1 = (const float*)d_in[9];
  const float* b1 = (const float*)d_in[10];
  const float* w2 = (const float*)d_in[11];
  const float* b2 = (const float*)d_in[12];
  float* out = (float*)d_out;
  float* ws  = (float*)d_ws;

  // workspace layout (float offsets)
  ushort_t* wt    = (ushort_t*)ws;                    // converted weights (bf16)
  ushort_t* abuf  = (ushort_t*)(ws + 1572864);        // attn-out / LN2-out bf16
  ushort_t* ffbf  = (ushort_t*)(ws + 2097152);        // FFN1 out bf16
  float* qb = ws + 4194304;                           // q (bf16) -> later h1 (fp32)
  float* kb = ws + 5242880;                           // k (bf16) -> later h2 (fp32)
  float* vb = ws + 6291456;                           // v (bf16)
  float* hb = ws + 7340032;                           // layer carry
  ushort_t* qbh = (ushort_t*)qb;
  ushort_t* kbh = (ushort_t*)kb;
  ushort_t* vbh = (ushort_t*)vb;

  const ushort_t* w1t_base = wt + 1048576;
  const ushort_t* w2t_base = wt + 2097152;

  const dim3 blk(256);
  wconv_kernel<<<768, blk, 0, stream>>>(wq, wk, wv, wo, w1, w2, wt);

  for (int l = 0; l < NLAYER; l++){
    const float* hin = (l == 0) ? x : hb;
    const ushort_t* lwq = wt + (size_t)(0*NLAYER + l)*65536;
    const ushort_t* lwk = wt + (size_t)(1*NLAYER + l)*65536;
    const ushort_t* lwv = wt + (size_t)(2*NLAYER + l)*65536;
    const ushort_t* lwo = wt + (size_t)(3*NLAYER + l)*65536;
    const ushort_t* lw1 = w1t_base + (size_t)l*262144;
    const ushort_t* lw2 = w2t_base + (size_t)l*262144;

    // q,k,v = LN(h)@W + b (fused LN1, bf16 out)
    qkv_kernel<<<dim3(4,128), blk, 0, stream>>>(hin, lwq, lwk, lwv,
        bq + (size_t)l*DIM, bk + (size_t)l*DIM, bv + (size_t)l*DIM, qbh, kbh, vbh);
    // attention (MFMA flash) -> bf16 abuf
    attn_kernel<<<dim3(SEQ/64, NH), blk, 0, stream>>>(qbh, kbh, vbh, abuf);
    // h1 = h + attn@wo + bo -> qb (fp32)
    gemm_kernel<<<dim3(4,128), blk, 0, stream>>>(abuf, lwo, bo + (size_t)l*DIM,
        hin, qb, nullptr, SEQ, DIM, DIM, 0);
    // h2 = LN(h1) -> kb (fp32) + abuf (bf16)
    ln_kernel<<<SEQ/4, blk, 0, stream>>>(qb, kb, abuf);
    // ff = gelu(h2@w1 + b1) -> bf16
    gemm_kernel<<<dim3(16,128), blk, 0, stream>>>(abuf, lw1, b1 + (size_t)l*FFD,
        nullptr, nullptr, ffbf, SEQ, FFD, DIM, 1);
    // h_out = h2 + ff@w2 + b2
    float* hout = (l == NLAYER-1) ? out : hb;
    gemm_kernel<<<dim3(4,128), blk, 0, stream>>>(ffbf, lw2, b2 + (size_t)l*DIM,
        kb, hout, nullptr, SEQ, DIM, FFD, 0);
  }
}

// Round 9
// 343.214 us; speedup vs baseline: 1.1237x; 1.0505x over previous
//
#include <hip/hip_runtime.h>
#include <math.h>

#define SEQ 4096
#define DIM 256
#define NH 8
#define DHD 32
#define FFD 1024
#define NLAYER 4

typedef unsigned short ushort_t;
typedef __attribute__((ext_vector_type(8))) short bf16x8;
typedef __attribute__((ext_vector_type(4))) float f32x4;

__device__ __forceinline__ float gelu_f(float x){
  const float c = 0.7978845608028654f; // sqrt(2/pi)
  float x3 = x*x*x;
  return 0.5f * x * (1.0f + tanhf(c*(x + 0.044715f*x3)));
}

__device__ __forceinline__ ushort_t f2b(float f){
  union { float f; unsigned u; } x; x.f = f;
  unsigned r = x.u + 0x7FFF + ((x.u >> 16) & 1);   // RNE
  return (ushort_t)(r >> 16);
}

// async 16B global->LDS (dest = wave-uniform base + lane*16, lane-contiguous)
__device__ __forceinline__ void gload16(void* lds, const void* g){
  __builtin_amdgcn_global_load_lds((const __attribute__((address_space(1))) void*)g,
                                   (__attribute__((address_space(3))) void*)lds, 16, 0, 0);
}

// XCD-bijective block swizzle: HW round-robins blockIdx across 8 XCDs; this
// remap gives each XCD a CONTIGUOUS chunk of work-ids so same-panel blocks
// share one L2. Bijective when nwg % 8 == 0 (all our grids are 512).
__device__ __forceinline__ int xcd_swz(int b, int nwg){
  return (b & 7)*(nwg >> 3) + (b >> 3);
}

// ---------------- weight convert + transpose: W[K][N] fp32 -> Wt[N][K] bf16 --
__global__ __launch_bounds__(256) void wconv_kernel(
    const float* __restrict__ wq, const float* __restrict__ wk,
    const float* __restrict__ wv, const float* __restrict__ wo,
    const float* __restrict__ w1, const float* __restrict__ w2,
    ushort_t* __restrict__ wt){
  __shared__ ushort_t tile[64][65];
  int b = blockIdx.x, tid = threadIdx.x;
  const float* src; ushort_t* dst; int K, N, tk, tn;
  if (b < 256){
    int m = b>>6, rem = b&63, l = rem>>4, t = rem&15;
    K = 256; N = 256; tk = t>>2; tn = t&3;
    const float* s4 = (m==0)?wq:(m==1)?wk:(m==2)?wv:wo;
    src = s4 + (size_t)l*65536;
    dst = wt + (size_t)(m*NLAYER + l)*65536;
  } else if (b < 512){
    int rem = b-256, l = rem>>6, t = rem&63;
    K = 256; N = 1024; tk = t>>4; tn = t&15;
    src = w1 + (size_t)l*262144;
    dst = wt + 1048576 + (size_t)l*262144;
  } else {
    int rem = b-512, l = rem>>6, t = rem&63;
    K = 1024; N = 256; tk = t>>2; tn = t&3;
    src = w2 + (size_t)l*262144;
    dst = wt + 2097152 + (size_t)l*262144;
  }
  int k0 = tk*64, n0 = tn*64;
  #pragma unroll
  for (int i=0;i<16;i++){
    int idx = tid + 256*i, row = idx>>6, col = idx&63;
    tile[row][col] = f2b(src[(size_t)(k0+row)*N + n0+col]);
  }
  __syncthreads();
  #pragma unroll
  for (int i=0;i<16;i++){
    int idx = tid + 256*i, nrow = idx>>6, kcol = idx&63;
    dst[(size_t)(n0+nrow)*K + k0+kcol] = tile[kcol][nrow];
  }
}

// ---------------- LayerNorm: fp32 in, fp32 + bf16 out (LN2) -----------------
__global__ __launch_bounds__(256) void ln_kernel(const float* __restrict__ x,
    float* __restrict__ yf, ushort_t* __restrict__ yb){
  int row  = blockIdx.x*4 + (threadIdx.x>>6);
  int lane = threadIdx.x & 63;
  const float4* xr = (const float4*)(x + (size_t)row*DIM);
  float4 v = xr[lane];
  float s  = v.x+v.y+v.z+v.w;
  float sq = v.x*v.x+v.y*v.y+v.z*v.z+v.w*v.w;
  #pragma unroll
  for(int off=32; off>0; off>>=1){
    s  += __shfl_down(s, off);
    sq += __shfl_down(sq, off);
  }
  s = __shfl(s, 0); sq = __shfl(sq, 0);
  float mean = s * (1.0f/DIM);
  float var  = sq * (1.0f/DIM) - mean*mean;
  float rinv = rsqrtf(var + 1e-5f);
  float4 o;
  o.x=(v.x-mean)*rinv; o.y=(v.y-mean)*rinv; o.z=(v.z-mean)*rinv; o.w=(v.w-mean)*rinv;
  if (yf) ((float4*)(yf + (size_t)row*DIM))[lane] = o;
  if (yb){
    ushort_t* yp = yb + (size_t)row*DIM + lane*4;
    yp[0]=f2b(o.x); yp[1]=f2b(o.y); yp[2]=f2b(o.z); yp[3]=f2b(o.w);
  }
}

// ---------------- bf16 MFMA GEMM: C = act(A @ Wt^T + bias (+R)) --------------
// M-tile 32, N-tile 64, K staged 256/step. Grid is always (4, M/32) = 512
// blocks here (wo, FFN2); work-id XCD-swizzled.
__global__ __launch_bounds__(256) void gemm_kernel(
    const ushort_t* __restrict__ A, const ushort_t* __restrict__ Wt,
    const float* __restrict__ bias, const float* __restrict__ R,
    float* __restrict__ Cf, ushort_t* __restrict__ Cb,
    int M, int N, int K, int act){
  __shared__ ushort_t As[32*256];
  __shared__ ushort_t Bs[64*256];
  int tid = threadIdx.x;
  int w = tid>>6, lane = tid&63;
  int wr = w>>1, wc = w&1;
  int q4 = lane>>4, u = lane&15;
  int fid = xcd_swz(blockIdx.y*4 + blockIdx.x, 512);  // grid (4, 128)
  int m0 = (fid>>2)*32, n0 = (fid&3)*64;
  f32x4 acc[2];
  acc[0] = (f32x4){0.f,0.f,0.f,0.f};
  acc[1] = (f32x4){0.f,0.f,0.f,0.f};

  for (int k0 = 0; k0 < K; k0 += 256){
    if (k0) __syncthreads();
    #pragma unroll
    for (int i=0;i<4;i++){          // As: 32 rows x 32 chunks of 16B
      int idx = tid + 256*i;
      int row = idx>>5, ch = idx&31;
      gload16(&As[idx*8], &A[(size_t)(m0+row)*K + k0 + ((ch^(row&7))*8)]);
    }
    #pragma unroll
    for (int i=0;i<8;i++){          // Bs: 64 rows x 32 chunks
      int idx = tid + 256*i;
      int row = idx>>5, ch = idx&31;
      gload16(&Bs[idx*8], &Wt[(size_t)(n0+row)*K + k0 + ((ch^(row&7))*8)]);
    }
    __syncthreads();
    #pragma unroll
    for (int kk=0;kk<8;kk++){
      int ar = wr*16 + u;
      bf16x8 af = *(const bf16x8*)&As[ar*256 + (((kk*4+q4)^(ar&7))*8)];
      #pragma unroll
      for (int j=0;j<2;j++){
        int br = wc*32 + j*16 + u;
        bf16x8 bf = *(const bf16x8*)&Bs[br*256 + (((kk*4+q4)^(br&7))*8)];
        acc[j] = __builtin_amdgcn_mfma_f32_16x16x32_bf16(af, bf, acc[j], 0, 0, 0);
      }
    }
  }
  #pragma unroll
  for (int j=0;j<2;j++){
    #pragma unroll
    for (int t=0;t<4;t++){
      int m = m0 + wr*16 + q4*4 + t;
      int n = n0 + wc*32 + j*16 + u;
      float val = acc[j][t] + bias[n];
      if (R)   val += R[(size_t)m*N + n];
      if (act) val = gelu_f(val);
      if (Cf)  Cf[(size_t)m*N + n] = val;
      if (Cb)  Cb[(size_t)m*N + n] = f2b(val);
    }
  }
}

// ---------------- FFN1, B-resident m-loop: ff = gelu(A@w1^T + b1) -----------
// grid (16, 32) = 512 blocks. Each block stages its w1 64-col panel ONCE and
// loops 4 m-subtiles of 32 rows (stage A -> barrier -> MFMA -> write ->
// barrier): 4x less w1 traffic, half the total LDS-staged bytes.
__global__ __launch_bounds__(256) void ffn1m_kernel(
    const ushort_t* __restrict__ A, const ushort_t* __restrict__ Wt,
    const float* __restrict__ bias, ushort_t* __restrict__ Cb){
  __shared__ ushort_t As[32*256];
  __shared__ ushort_t Bs[64*256];
  int tid = threadIdx.x;
  int w = tid>>6, lane = tid&63;
  int wr = w>>1, wc = w&1;
  int q4 = lane>>4, u = lane&15;
  int fid = xcd_swz(blockIdx.y*16 + blockIdx.x, 512);  // grid (16, 32)
  int n0 = (fid & 15)*64;
  int mg = (fid >> 4);                                  // 32 groups x 128 rows
  #pragma unroll
  for (int i=0;i<8;i++){          // Bs: w1 panel, staged once
    int idx = tid + 256*i;
    int row = idx>>5, ch = idx&31;
    gload16(&Bs[idx*8], &Wt[(size_t)(n0+row)*DIM + ((ch^(row&7))*8)]);
  }
  for (int ms=0; ms<4; ms++){
    int m0 = mg*128 + ms*32;
    #pragma unroll
    for (int i=0;i<4;i++){        // As: 32 rows
      int idx = tid + 256*i;
      int row = idx>>5, ch = idx&31;
      gload16(&As[idx*8], &A[(size_t)(m0+row)*DIM + ((ch^(row&7))*8)]);
    }
    __syncthreads();              // A (and first-iter B) landed; waves synced
    f32x4 acc[2];
    acc[0]=(f32x4){0.f,0.f,0.f,0.f}; acc[1]=(f32x4){0.f,0.f,0.f,0.f};
    #pragma unroll
    for (int kk=0;kk<8;kk++){
      int ar = wr*16 + u;
      bf16x8 af = *(const bf16x8*)&As[ar*256 + (((kk*4+q4)^(ar&7))*8)];
      #pragma unroll
      for (int j=0;j<2;j++){
        int br = wc*32 + j*16 + u;
        bf16x8 bf = *(const bf16x8*)&Bs[br*256 + (((kk*4+q4)^(br&7))*8)];
        acc[j] = __builtin_amdgcn_mfma_f32_16x16x32_bf16(af, bf, acc[j], 0, 0, 0);
      }
    }
    #pragma unroll
    for (int j=0;j<2;j++)
      #pragma unroll
      for (int t=0;t<4;t++){
        int m = m0 + wr*16 + q4*4 + t;
        int n = n0 + wc*32 + j*16 + u;
        Cb[(size_t)m*FFD + n] = f2b(gelu_f(acc[j][t] + bias[n]));
      }
    if (ms < 3) __syncthreads();  // all waves done reading As before restage
  }
}

// ---------------- fused LN + QKV: q/k/v = LN(h) @ W + b, bf16 out -----------
__global__ __launch_bounds__(256) void qkv_kernel(
    const float* __restrict__ hin,
    const ushort_t* __restrict__ wtq, const ushort_t* __restrict__ wtk, const ushort_t* __restrict__ wtv,
    const float* __restrict__ bqp, const float* __restrict__ bkp, const float* __restrict__ bvp,
    ushort_t* __restrict__ qo, ushort_t* __restrict__ ko, ushort_t* __restrict__ vo){
  __shared__ ushort_t As[32*256];
  __shared__ ushort_t Bs[64*256];
  int tid = threadIdx.x;
  int w = tid>>6, lane = tid&63;
  int wr = w>>1, wc = w&1;
  int q4 = lane>>4, u = lane&15;
  int fid = xcd_swz(blockIdx.y*4 + blockIdx.x, 512);  // grid (4, 128)
  int m0 = (fid>>2)*32, n0 = (fid&3)*64;

  // async-stage Bs first so HBM latency hides under the LN compute
  #pragma unroll
  for (int i=0;i<8;i++){
    int idx = tid + 256*i;
    int row = idx>>5, ch = idx&31;
    gload16(&Bs[idx*8], &wtq[(size_t)(n0+row)*DIM + ((ch^(row&7))*8)]);
  }
  // LN rows m0..m0+31: wave w handles rows w*8..w*8+7, full-wave reduce
  #pragma unroll
  for (int r=0;r<8;r++){
    int row = w*8 + r;
    float4 v = *(const float4*)&hin[(size_t)(m0+row)*DIM + lane*4];
    float s  = v.x+v.y+v.z+v.w;
    float sq = v.x*v.x+v.y*v.y+v.z*v.z+v.w*v.w;
    #pragma unroll
    for (int off=32; off>0; off>>=1){ s += __shfl_down(s,off); sq += __shfl_down(sq,off); }
    s = __shfl(s,0); sq = __shfl(sq,0);
    float mean = s*(1.0f/DIM), var = sq*(1.0f/DIM) - mean*mean;
    float rinv = rsqrtf(var + 1e-5f);
    int ch = lane>>1, half = lane&1;
    ushort4 o4;
    o4.x = f2b((v.x-mean)*rinv); o4.y = f2b((v.y-mean)*rinv);
    o4.z = f2b((v.z-mean)*rinv); o4.w = f2b((v.w-mean)*rinv);
    *(ushort4*)&As[row*256 + ((ch^(row&7))*8 + half*4)] = o4;
  }
  __syncthreads();

  #pragma unroll
  for (int z=0; z<3; z++){
    const float* bias = (z==0)?bqp:(z==1)?bkp:bvp;
    ushort_t* Cb      = (z==0)?qo :(z==1)?ko :vo;
    f32x4 acc[2];
    acc[0]=(f32x4){0.f,0.f,0.f,0.f}; acc[1]=(f32x4){0.f,0.f,0.f,0.f};
    #pragma unroll
    for (int kk=0;kk<8;kk++){
      int ar = wr*16 + u;
      bf16x8 af = *(const bf16x8*)&As[ar*256 + (((kk*4+q4)^(ar&7))*8)];
      #pragma unroll
      for (int j=0;j<2;j++){
        int br = wc*32 + j*16 + u;
        bf16x8 bf = *(const bf16x8*)&Bs[br*256 + (((kk*4+q4)^(br&7))*8)];
        acc[j] = __builtin_amdgcn_mfma_f32_16x16x32_bf16(af, bf, acc[j], 0, 0, 0);
      }
    }
    if (z < 2){
      __syncthreads();   // all waves' Bs reads complete
      const ushort_t* Wn = (z==0)?wtk:wtv;
      #pragma unroll
      for (int i=0;i<8;i++){
        int idx = tid + 256*i;
        int row = idx>>5, ch = idx&31;
        gload16(&Bs[idx*8], &Wn[(size_t)(n0+row)*DIM + ((ch^(row&7))*8)]);
      }
    }
    #pragma unroll
    for (int j=0;j<2;j++)
      #pragma unroll
      for (int t=0;t<4;t++){
        int m = m0 + wr*16 + q4*4 + t;
        int n = n0 + wc*32 + j*16 + u;
        Cb[(size_t)m*DIM + n] = f2b(acc[j][t] + bias[n]);
      }
    if (z < 2) __syncthreads();   // next B landed (vmcnt drained)
  }
}

// ---------------- sliding-window attention, bf16 MFMA flash-style ----------
// grid (64, 8) flat 512, XCD-swizzled so each XCD owns one head's q-tiles
// (shared K/V window stays in its L2). Double-buffered K/V, 1 barrier/tile.
__global__ __launch_bounds__(256) void attn_kernel(
    const ushort_t* __restrict__ q, const ushort_t* __restrict__ k,
    const ushort_t* __restrict__ v, ushort_t* __restrict__ out){
  int fid = xcd_swz(blockIdx.y*64 + blockIdx.x, 512);
  int q0 = (fid & 63) * 64;
  int h  = fid >> 6;
  int tid = threadIdx.x;
  int w = tid >> 6;
  int lane = tid & 63;
  int u = lane & 15, q4 = lane >> 4;

  __shared__ ushort_t Ks[2][64][40];    // [key][dh], 80B rows
  __shared__ ushort_t Vt[2][32][72];    // [dh][key], 144B rows
  __shared__ ushort_t Pw[4][16][72];    // per-wave P (wave-private)

  bf16x8 aq = *(const bf16x8*)(q + (size_t)(q0 + w*16 + u)*DIM + h*DHD + q4*8);

  float m[4], l[4];
  f32x4 acc[2];
  #pragma unroll
  for (int t=0;t<4;t++){ m[t] = -INFINITY; l[t] = 0.f; }
  acc[0] = (f32x4){0.f,0.f,0.f,0.f};
  acc[1] = (f32x4){0.f,0.f,0.f,0.f};

  const float sl2 = 0.25510703448358519f; // (1/sqrt(32)) * log2(e)

  int lo = q0 - 256; if (lo < 0) lo = 0;
  int hi = q0 + 63 + 256; if (hi > SEQ-1) hi = SEQ-1;
  int kt0 = (lo >> 6) << 6;
  int kt1 = (hi >> 6) << 6;

  int key = tid >> 2, d0 = (tid & 3) * 8;  // K-staging map
  int vd0 = w * 8;                          // V-staging: wave w -> dh slice

  // prologue: stage tile 0 into buf 0
  bf16x8 kr = *(const bf16x8*)(k + (size_t)(kt0+key)*DIM + h*DHD + d0);
  bf16x8 vr = *(const bf16x8*)(v + (size_t)(kt0+lane)*DIM + h*DHD + vd0);
  *(bf16x8*)&Ks[0][key][d0] = kr;
  #pragma unroll
  for (int j=0;j<8;j++) Vt[0][vd0+j][lane] = (ushort_t)vr[j];

  int p = 0;
  for (int kt = kt0; kt <= kt1; kt += 64, p ^= 1){
    __syncthreads();   // tile kt visible in buf p; all prior buf p^1 reads done
    bool have_next = (kt + 64 <= kt1);
    if (have_next){    // issue next tile's loads early; land under softmax+PV
      kr = *(const bf16x8*)(k + (size_t)(kt+64+key)*DIM + h*DHD + d0);
      vr = *(const bf16x8*)(v + (size_t)(kt+64+lane)*DIM + h*DHD + vd0);
    }

    f32x4 sc[4];
    #pragma unroll
    for (int t4=0;t4<4;t4++){
      bf16x8 bk = *(const bf16x8*)&Ks[p][t4*16 + u][q4*8];
      sc[t4] = __builtin_amdgcn_mfma_f32_16x16x32_bf16(aq, bk, (f32x4){0.f,0.f,0.f,0.f}, 0, 0, 0);
    }

    bool needs_mask = (kt < q0-192) || (kt > q0+192);
    #pragma unroll
    for (int t=0;t<4;t++){
      float mx = -INFINITY;
      if (needs_mask){
        int q_idx = q0 + w*16 + q4*4 + t;
        #pragma unroll
        for (int t4=0;t4<4;t4++){
          float s = sc[t4][t] * sl2;
          int k_idx = kt + t4*16 + u;
          int diff = q_idx - k_idx; if (diff < 0) diff = -diff;
          if (diff > 256) s = -INFINITY;
          sc[t4][t] = s;
          mx = fmaxf(mx, s);
        }
      } else {
        #pragma unroll
        for (int t4=0;t4<4;t4++){
          float s = sc[t4][t] * sl2;
          sc[t4][t] = s;
          mx = fmaxf(mx, s);
        }
      }
      mx = fmaxf(mx, __shfl_xor(mx, 1));
      mx = fmaxf(mx, __shfl_xor(mx, 2));
      mx = fmaxf(mx, __shfl_xor(mx, 4));
      mx = fmaxf(mx, __shfl_xor(mx, 8));
      float nm = fmaxf(m[t], mx);
      float al = exp2f(m[t] - nm);
      float rs = 0.f;
      #pragma unroll
      for (int t4=0;t4<4;t4++){
        float pv = exp2f(sc[t4][t] - nm);
        rs += pv;
        Pw[w][q4*4+t][t4*16+u] = f2b(pv);
      }
      rs += __shfl_xor(rs, 1);
      rs += __shfl_xor(rs, 2);
      rs += __shfl_xor(rs, 4);
      rs += __shfl_xor(rs, 8);
      l[t] = l[t]*al + rs;
      m[t] = nm;
      acc[0][t] *= al;
      acc[1][t] *= al;
    }
    // PV (Pw wave-private -> no barrier; Vt fenced by loop-top barrier)
    #pragma unroll
    for (int kk=0;kk<2;kk++){
      bf16x8 ap = *(const bf16x8*)&Pw[w][u][kk*32 + q4*8];
      #pragma unroll
      for (int d=0; d<2; d++){
        bf16x8 bvf = *(const bf16x8*)&Vt[p][d*16 + u][kk*32 + q4*8];
        acc[d] = __builtin_amdgcn_mfma_f32_16x16x32_bf16(ap, bvf, acc[d], 0, 0, 0);
      }
    }
    if (have_next){    // write next tile into the other buffer
      *(bf16x8*)&Ks[p^1][key][d0] = kr;
      #pragma unroll
      for (int j=0;j<8;j++) Vt[p^1][vd0+j][lane] = (ushort_t)vr[j];
    }
  }

  float rl[4];
  #pragma unroll
  for (int t=0;t<4;t++) rl[t] = 1.0f / l[t];
  #pragma unroll
  for (int d=0; d<2; d++)
    #pragma unroll
    for (int t=0;t<4;t++)
      out[(size_t)(q0 + w*16 + q4*4 + t)*DIM + h*DHD + d*16 + u] = f2b(acc[d][t]*rl[t]);
}

extern "C" void kernel_launch(void* const* d_in, const int* in_sizes, int n_in,
                              void* d_out, int out_size, void* d_ws, size_t ws_size,
                              hipStream_t stream) {
  const float* x  = (const float*)d_in[0];
  const float* wq = (const float*)d_in[1];
  const float* bq = (const float*)d_in[2];
  const float* wk = (const float*)d_in[3];
  const float* bk = (const float*)d_in[4];
  const float* wv = (const float*)d_in[5];
  const float* bv = (const float*)d_in[6];
  const float* wo = (const float*)d_in[7];
  const float* bo = (const float*)d_in[8];
  const float* w1 = (const float*)d_in[9];
  const float* b1 = (const float*)d_in[10];
  const float* w2 = (const float*)d_in[11];
  const float* b2 = (const float*)d_in[12];
  float* out = (float*)d_out;
  float* ws  = (float*)d_ws;

  // workspace layout (float offsets)
  ushort_t* wt    = (ushort_t*)ws;                    // converted weights (bf16)
  ushort_t* abuf  = (ushort_t*)(ws + 1572864);        // attn-out / LN2-out bf16
  ushort_t* ffbf  = (ushort_t*)(ws + 2097152);        // FFN1 out bf16
  float* qb = ws + 4194304;                           // q (bf16) -> later h1 (fp32)
  float* kb = ws + 5242880;                           // k (bf16) -> later h2 (fp32)
  float* vb = ws + 6291456;                           // v (bf16)
  float* hb = ws + 7340032;                           // layer carry
  ushort_t* qbh = (ushort_t*)qb;
  ushort_t* kbh = (ushort_t*)kb;
  ushort_t* vbh = (ushort_t*)vb;

  const ushort_t* w1t_base = wt + 1048576;
  const ushort_t* w2t_base = wt + 2097152;

  const dim3 blk(256);
  wconv_kernel<<<768, blk, 0, stream>>>(wq, wk, wv, wo, w1, w2, wt);

  for (int l = 0; l < NLAYER; l++){
    const float* hin = (l == 0) ? x : hb;
    const ushort_t* lwq = wt + (size_t)(0*NLAYER + l)*65536;
    const ushort_t* lwk = wt + (size_t)(1*NLAYER + l)*65536;
    const ushort_t* lwv = wt + (size_t)(2*NLAYER + l)*65536;
    const ushort_t* lwo = wt + (size_t)(3*NLAYER + l)*65536;
    const ushort_t* lw1 = w1t_base + (size_t)l*262144;
    const ushort_t* lw2 = w2t_base + (size_t)l*262144;

    // q,k,v = LN(h)@W + b (fused LN1, bf16 out)
    qkv_kernel<<<dim3(4,128), blk, 0, stream>>>(hin, lwq, lwk, lwv,
        bq + (size_t)l*DIM, bk + (size_t)l*DIM, bv + (size_t)l*DIM, qbh, kbh, vbh);
    // attention (MFMA flash) -> bf16 abuf
    attn_kernel<<<dim3(SEQ/64, NH), blk, 0, stream>>>(qbh, kbh, vbh, abuf);
    // h1 = h + attn@wo + bo -> qb (fp32)
    gemm_kernel<<<dim3(4,128), blk, 0, stream>>>(abuf, lwo, bo + (size_t)l*DIM,
        hin, qb, nullptr, SEQ, DIM, DIM, 0);
    // h2 = LN(h1) -> kb (fp32) + abuf (bf16)
    ln_kernel<<<SEQ/4, blk, 0, stream>>>(qb, kb, abuf);
    // ff = gelu(h2@w1 + b1) -> bf16 (B-resident m-loop)
    ffn1m_kernel<<<dim3(16,32), blk, 0, stream>>>(abuf, lw1, b1 + (size_t)l*FFD,
        ffbf);
    // h_out = h2 + ff@w2 + b2
    float* hout = (l == NLAYER-1) ? out : hb;
    gemm_kernel<<<dim3(4,128), blk, 0, stream>>>(ffbf, lw2, b2 + (size_t)l*DIM,
        kb, hout, nullptr, SEQ, DIM, FFD, 0);
  }
}